// Round 8
// baseline (415.917 us; speedup 1.0000x reference)
//
#include <hip/hip_runtime.h>

#define DEV __device__ __forceinline__

using f16x8 = _Float16 __attribute__((ext_vector_type(8)));
using f16x4 = _Float16 __attribute__((ext_vector_type(4)));
using f32x4 = float __attribute__((ext_vector_type(4)));

DEV f32x4 mfma16(f16x8 a, f16x8 b, f32x4 c) {
    return __builtin_amdgcn_mfma_f32_16x16x32_f16(a, b, c, 0, 0, 0);
}

DEV void gload16(const void* g, void* l) {
    __builtin_amdgcn_global_load_lds(
        (const __attribute__((address_space(1))) void*)g,
        (__attribute__((address_space(3))) void*)l, 16, 0, 0);
}

// ---------------------------------------------------------------------------
// 256x256-tile GEMM, deep-pipelined (T3/T4): C[M,N] = A[M,K] * Bt[N,K]^T.
// 512 threads = 8 waves (2M x 4N); per-wave output 128x64 (acc[8][4]).
// K is consumed in 32-wide sub-tiles; 4-slot LDS ring (A 16K + B 16K per
// slot = 128 KiB, 1 block/CU). Pipeline: prologue stages s0..s2; iteration s:
//   vmcnt(8) [counted: 2 sub-tiles stay in flight] -> s_barrier ->
//   stage(s+3) into the slot the barrier just freed -> 12 ds_read_b128 ->
//   lgkmcnt(0)+sched_barrier -> setprio(1) 32 MFMA setprio(0).
// LDS swizzle: byte ^= ((row>>1)&3)<<4 on 64B rows (inverse on global source,
// same XOR on reads) -> exactly 2-way banks (free).
// MODE 0: QKV scatter epilogue (q pre-scaled by log2e/sqrt(D))
// MODE 2: ff1 = relu(acc + b1) -> f16
// ---------------------------------------------------------------------------
DEV void stage_sub(const _Float16* __restrict__ A, const _Float16* __restrict__ Bt,
                   int K, int m0, int n0, int s, char* slot, int tid)
{
#pragma unroll
    for (int p = 0; p < 2; ++p) {
        const int off  = p * 8192 + tid * 16;
        const int row  = off >> 6;
        const int colb = (off & 63) ^ (((row >> 1) & 3) << 4);
        gload16(A + (size_t)(m0 + row) * K + s * 32 + (colb >> 1), slot + off);
    }
#pragma unroll
    for (int p = 0; p < 2; ++p) {
        const int off  = p * 8192 + tid * 16;
        const int row  = off >> 6;
        const int colb = (off & 63) ^ (((row >> 1) & 3) << 4);
        gload16(Bt + (size_t)(n0 + row) * K + s * 32 + (colb >> 1), slot + 16384 + off);
    }
}

template <int MODE>
__global__ __launch_bounds__(512, 2) void gemm256(
    const _Float16* __restrict__ A, const _Float16* __restrict__ Bt,
    int M, int N, int K,
    const float* __restrict__ ep0,
    void* __restrict__ o0, void* __restrict__ o1, void* __restrict__ o2)
{
    __shared__ __align__(16) char smem[131072];   // 4 slots x (A 16K + B 16K)
    const int tid = threadIdx.x;
    const int wid = tid >> 6, lane = tid & 63;
    const int l16 = lane & 15, g = lane >> 4;
    const int wr = wid >> 2, wc = wid & 3;
    const int m0 = blockIdx.x * 256, n0 = blockIdx.y * 256;
    const int S = K >> 5;                          // number of 32-K sub-tiles

    f32x4 acc[8][4] = {};

    // lane-constant read offsets (swizzled)
    const int swz   = ((l16 >> 1) & 3) << 4;
    const int aoffb = (wr * 128 + l16) * 64 + ((g * 16) ^ swz);
    const int boffb = 16384 + (wc * 64 + l16) * 64 + ((g * 16) ^ swz);

    // prologue: stage sub-tiles 0,1,2
    stage_sub(A, Bt, K, m0, n0, 0, smem, tid);
    if (S > 1) stage_sub(A, Bt, K, m0, n0, 1, smem + 32768, tid);
    if (S > 2) stage_sub(A, Bt, K, m0, n0, 2, smem + 65536, tid);

    for (int s = 0; s < S; ++s) {
        if (s + 3 <= S)      asm volatile("s_waitcnt vmcnt(8)" ::: "memory");
        else if (s + 2 == S) asm volatile("s_waitcnt vmcnt(4)" ::: "memory");
        else                 asm volatile("s_waitcnt vmcnt(0)" ::: "memory");
        __builtin_amdgcn_s_barrier();
        __builtin_amdgcn_sched_barrier(0);

        char* slot = smem + ((s & 3) << 15);
        if (s + 3 < S)
            stage_sub(A, Bt, K, m0, n0, s + 3, smem + (((s + 3) & 3) << 15), tid);

        f16x8 af[8], bf[4];
#pragma unroll
        for (int mi = 0; mi < 8; ++mi)
            af[mi] = *(const f16x8*)(slot + aoffb + mi * 1024);
#pragma unroll
        for (int nj = 0; nj < 4; ++nj)
            bf[nj] = *(const f16x8*)(slot + boffb + nj * 1024);
        asm volatile("s_waitcnt lgkmcnt(0)" ::: "memory");
        __builtin_amdgcn_sched_barrier(0);

        __builtin_amdgcn_s_setprio(1);
#pragma unroll
        for (int mi = 0; mi < 8; ++mi)
#pragma unroll
            for (int nj = 0; nj < 4; ++nj)
                acc[mi][nj] = mfma16(af[mi], bf[nj], acc[mi][nj]);
        __builtin_amdgcn_s_setprio(0);
        __builtin_amdgcn_sched_barrier(0);
    }

#pragma unroll
    for (int mi = 0; mi < 8; ++mi) {
#pragma unroll
        for (int nj = 0; nj < 4; ++nj) {
#pragma unroll
            for (int r = 0; r < 4; ++r) {
                const int m = m0 + wr * 128 + mi * 16 + g * 4 + r;
                const int n = n0 + wc * 64 + nj * 16 + l16;
                const float val = acc[mi][nj][r];
                if constexpr (MODE == 0) {
                    const int b = m >> 11, ss = m & 2047;
                    const int which = n >> 10, hh = (n >> 6) & 15, dd = n & 63;
                    const size_t bh = (size_t)(b * 16 + hh);
                    if (which == 0) {
                        ((_Float16*)o0)[(bh * 2048 + ss) * 64 + dd] =
                            (_Float16)(val * 0.04508422f);   // log2e/sqrt(D)
                    } else if (which == 1) {
                        ((_Float16*)o1)[(bh * 2048 + ss) * 64 + dd] = (_Float16)val;
                    } else {
                        ((_Float16*)o2)[(bh * 64 + dd) * 2048 + ss] = (_Float16)val;
                    }
                } else {  // MODE 2
                    float v = val + ep0[n];
                    ((_Float16*)o0)[(size_t)m * N + n] = (_Float16)(v > 0.f ? v : 0.f);
                }
            }
        }
    }
}

// ---------------------------------------------------------------------------
// GEMM: 128x128 tile (R5-exact) — kept for Wo (MODE 1) and FFN2 (MODE 3),
// whose N=1024 grids (512 blocks) fill the GPU better than 256^2 would.
// MODE 1: resid1 = acc + x      (ep0 = x fp32, o0 = fp32)
// MODE 3: resid2 = acc + b2 + h1f (ep0 = b2, ep1 = h1f, o0 = fp32)
// ---------------------------------------------------------------------------
template <int MODE>
__global__ __launch_bounds__(256, 2) void gemm_bt(
    const _Float16* __restrict__ A, const _Float16* __restrict__ Bt,
    int M, int N, int K,
    const float* __restrict__ ep0, const float* __restrict__ ep1,
    void* __restrict__ o0)
{
    __shared__ __align__(16) _Float16 As[128 * 64];
    __shared__ __align__(16) _Float16 Bs[128 * 64];
    const int tid  = threadIdx.x;
    const int wave = tid >> 6, lane = tid & 63;
    const int l16  = lane & 15, g = lane >> 4;
    const int m0 = blockIdx.x * 128, n0 = blockIdx.y * 128;
    const int wm = (wave >> 1) * 64, wn = (wave & 1) * 64;

    f32x4 acc[4][4] = {};

    for (int kt = 0; kt < K; kt += 64) {
#pragma unroll
        for (int it = 0; it < 4; ++it) {  // stage A tile (16 KB)
            const int off  = it * 4096 + tid * 16;
            const int row  = off >> 7;
            const int colb = (off & 127) ^ ((row & 7) << 4);
            gload16(A + (size_t)(m0 + row) * K + kt + (colb >> 1), (char*)As + off);
        }
#pragma unroll
        for (int it = 0; it < 4; ++it) {  // stage B tile
            const int off  = it * 4096 + tid * 16;
            const int row  = off >> 7;
            const int colb = (off & 127) ^ ((row & 7) << 4);
            gload16(Bt + (size_t)(n0 + row) * K + kt + (colb >> 1), (char*)Bs + off);
        }
        __syncthreads();
#pragma unroll
        for (int kk = 0; kk < 2; ++kk) {
            f16x8 af[4], bfv[4];
#pragma unroll
            for (int i = 0; i < 4; ++i) {
                const int ar = wm + i * 16 + l16;
                const int cb = ((kk * 32 + g * 8) << 1) ^ ((ar & 7) << 4);
                af[i] = *(const f16x8*)((const char*)As + (ar << 7) + cb);
            }
#pragma unroll
            for (int j = 0; j < 4; ++j) {
                const int br = wn + j * 16 + l16;
                const int cb = ((kk * 32 + g * 8) << 1) ^ ((br & 7) << 4);
                bfv[j] = *(const f16x8*)((const char*)Bs + (br << 7) + cb);
            }
#pragma unroll
            for (int i = 0; i < 4; ++i)
#pragma unroll
                for (int j = 0; j < 4; ++j)
                    acc[i][j] = mfma16(af[i], bfv[j], acc[i][j]);
        }
        __syncthreads();
    }

#pragma unroll
    for (int i = 0; i < 4; ++i) {
#pragma unroll
        for (int j = 0; j < 4; ++j) {
#pragma unroll
            for (int r = 0; r < 4; ++r) {
                const int m = m0 + wm + i * 16 + g * 4 + r;
                const int n = n0 + wn + j * 16 + l16;
                const float val = acc[i][j][r];
                if constexpr (MODE == 1) {
                    const size_t idx = (size_t)m * N + n;
                    ((float*)o0)[idx] = val + ep0[idx];
                } else {
                    const size_t idx = (size_t)m * N + n;
                    ((float*)o0)[idx] = val + ep0[n] + ep1[idx];
                }
            }
        }
    }
}

// stage one 64-key K,V tile (8 KB each) into the given LDS buffers.
DEV void stage_kv(const _Float16* __restrict__ Kh, const _Float16* __restrict__ Vh,
                  int kb0, char* ksb, char* vsb, int tid)
{
#pragma unroll
    for (int it = 0; it < 2; ++it) {
        const int off  = it * 4096 + tid * 16;
        const int row  = off >> 7;
        const int colb = (off & 127) ^ ((row & 7) << 4);
        gload16(Kh + (size_t)(kb0 + row) * 64 + (colb >> 1), ksb + off);
    }
#pragma unroll
    for (int it = 0; it < 2; ++it) {
        const int off  = it * 4096 + tid * 16;
        const int row  = off >> 7;
        const int colb = (off & 127) ^ ((row & 7) << 4);
        gload16(Vh + (size_t)row * 2048 + kb0 + (colb >> 1), vsb + off);
    }
}

// ---------------------------------------------------------------------------
// Flash attention (R7 structure; exp2 now via __builtin_amdgcn_exp2f — the
// R7 exp2f libcall was the VALU regression).
// ---------------------------------------------------------------------------
__global__ __launch_bounds__(256, 4) void attn_kernel(
    const _Float16* __restrict__ Q, const _Float16* __restrict__ Kb,
    const _Float16* __restrict__ Vt, _Float16* __restrict__ ctx)
{
    __shared__ __align__(16) char smem[40960];
    const int tid = threadIdx.x;
    const int w = tid >> 6, lane = tid & 63;
    const int l16 = lane & 15, g = lane >> 4;
    const int bh = blockIdx.y;
    const int b = bh >> 4, h = bh & 15;
    const int tA = blockIdx.x;              // 0..15

    const _Float16* Kh = Kb + (size_t)bh * 2048 * 64;
    const _Float16* Vh = Vt + (size_t)bh * 64 * 2048;
    const int swl = (l16 & 7) << 4;
    char* prow = smem + 32768 + w * 2048 + l16 * 128;

    for (int half = 0; half < 2; ++half) {
        const int T = half ? (31 - tA) : tA;
        const int qbase = T * 64 + w * 16;
        const int qg = qbase + l16;
        const int nt = T + 1;

        const _Float16* qrow = Q + ((size_t)bh * 2048 + qg) * 64;
        const f16x8 qf0 = *(const f16x8*)(qrow + g * 8);
        const f16x8 qf1 = *(const f16x8*)(qrow + 32 + g * 8);

        f32x4 cacc[4] = {};
        float m_run = -INFINITY, l_run = 0.f;

        stage_kv(Kh, Vh, 0, smem, smem + 16384, tid);
        if (nt > 1) stage_kv(Kh, Vh, 64, smem + 8192, smem + 24576, tid);

        for (int kt = 0; kt < nt; ++kt) {
            const int bufo = (kt & 1) << 13;
            char* kbuf = smem + bufo;
            char* vbuf = smem + 16384 + bufo;

            if (kt + 1 < nt) asm volatile("s_waitcnt vmcnt(4)" ::: "memory");
            else             asm volatile("s_waitcnt vmcnt(0)" ::: "memory");
            __builtin_amdgcn_s_barrier();
            __builtin_amdgcn_sched_barrier(0);

            f32x4 st[4];
            __builtin_amdgcn_s_setprio(1);
#pragma unroll
            for (int s = 0; s < 4; ++s) {
                const char* kr = kbuf + (16 * s + l16) * 128;
                const f16x8 klo = *(const f16x8*)(kr + ((g * 16) ^ swl));
                const f16x8 khi = *(const f16x8*)(kr + ((64 + g * 16) ^ swl));
                f32x4 a0 = {0.f, 0.f, 0.f, 0.f};
                a0 = mfma16(klo, qf0, a0);
                st[s] = mfma16(khi, qf1, a0);
            }
            __builtin_amdgcn_s_setprio(0);

            if (kt == nt - 1) {
#pragma unroll
                for (int s = 0; s < 4; ++s)
#pragma unroll
                    for (int r = 0; r < 4; ++r) {
                        const int kg = kt * 64 + s * 16 + g * 4 + r;
                        if (kg > qg) st[s][r] = -INFINITY;
                    }
            }

            float tmax = st[0][0];
#pragma unroll
            for (int s = 0; s < 4; ++s)
#pragma unroll
                for (int r = 0; r < 4; ++r) tmax = fmaxf(tmax, st[s][r]);
            tmax = fmaxf(tmax, __shfl_xor(tmax, 16));
            tmax = fmaxf(tmax, __shfl_xor(tmax, 32));

            if (__any(tmax > m_run)) {
                const float m_new = fmaxf(m_run, tmax);
                const float alpha = __builtin_amdgcn_exp2f(m_run - m_new);
                m_run = m_new;
                l_run *= alpha;
                f32x4 al;
#pragma unroll
                for (int r = 0; r < 4; ++r) al[r] = __shfl(alpha, g * 4 + r);
#pragma unroll
                for (int jt = 0; jt < 4; ++jt)
#pragma unroll
                    for (int r = 0; r < 4; ++r) cacc[jt][r] *= al[r];
            }

            float tsum = 0.f;
#pragma unroll
            for (int s = 0; s < 4; ++s) {
                f16x4 p;
#pragma unroll
                for (int r = 0; r < 4; ++r) {
                    const float e = __builtin_amdgcn_exp2f(st[s][r] - m_run);
                    tsum += e;
                    p[r] = (_Float16)e;
                }
                *(f16x4*)(prow + ((s * 32 + g * 8) ^ swl)) = p;
            }
            tsum += __shfl_xor(tsum, 16);
            tsum += __shfl_xor(tsum, 32);
            l_run += tsum;

            const f16x8 pf0 = *(const f16x8*)(prow + ((g * 16) ^ swl));
            const f16x8 pf1 = *(const f16x8*)(prow + ((64 + g * 16) ^ swl));
            __builtin_amdgcn_s_setprio(1);
#pragma unroll
            for (int jt = 0; jt < 4; ++jt) {
                const char* vr = vbuf + (jt * 16 + l16) * 128;
                const f16x8 vlo = *(const f16x8*)(vr + ((g * 16) ^ swl));
                const f16x8 vhi = *(const f16x8*)(vr + ((64 + g * 16) ^ swl));
                cacc[jt] = mfma16(pf0, vlo, cacc[jt]);
                cacc[jt] = mfma16(pf1, vhi, cacc[jt]);
            }
            __builtin_amdgcn_s_setprio(0);

            __builtin_amdgcn_sched_barrier(0);
            __builtin_amdgcn_s_barrier();
            if (kt + 2 < nt)
                stage_kv(Kh, Vh, (kt + 2) * 64, kbuf, vbuf, tid);
        }

        __builtin_amdgcn_s_barrier();

        const float inv = 1.f / l_run;
        f32x4 il;
#pragma unroll
        for (int r = 0; r < 4; ++r) il[r] = __shfl(inv, g * 4 + r);
#pragma unroll
        for (int jt = 0; jt < 4; ++jt)
#pragma unroll
            for (int r = 0; r < 4; ++r)
                ctx[((size_t)b * 2048 + qbase + g * 4 + r) * 1024 + h * 64 + jt * 16 + l16]
                    = (_Float16)(cacc[jt][r] * il[r]);
    }
}

// ---------------------------------------------------------------------------
// LayerNorm over rows of 1024 fp32; optional fp32 and f16 outputs.
// ---------------------------------------------------------------------------
__global__ __launch_bounds__(256) void ln_kernel(
    const float* __restrict__ in, const float* __restrict__ gam, const float* __restrict__ bet,
    float* __restrict__ out32, _Float16* __restrict__ out16)
{
    const int row = blockIdx.x, tid = threadIdx.x;
    const float4 x = ((const float4*)(in + (size_t)row * 1024))[tid];
    float s  = x.x + x.y + x.z + x.w;
    float s2 = x.x * x.x + x.y * x.y + x.z * x.z + x.w * x.w;
#pragma unroll
    for (int o = 32; o > 0; o >>= 1) {
        s  += __shfl_xor(s, o);
        s2 += __shfl_xor(s2, o);
    }
    __shared__ float red[8];
    if ((tid & 63) == 0) { red[tid >> 6] = s; red[4 + (tid >> 6)] = s2; }
    __syncthreads();
    const float S  = red[0] + red[1] + red[2] + red[3];
    const float S2 = red[4] + red[5] + red[6] + red[7];
    const float mu = S * (1.f / 1024.f);
    const float ir = rsqrtf(S2 * (1.f / 1024.f) - mu * mu + 1e-5f);
    const float4 gv = ((const float4*)gam)[tid];
    const float4 bv = ((const float4*)bet)[tid];
    float4 o;
    o.x = (x.x - mu) * ir * gv.x + bv.x;
    o.y = (x.y - mu) * ir * gv.y + bv.y;
    o.z = (x.z - mu) * ir * gv.z + bv.z;
    o.w = (x.w - mu) * ir * gv.w + bv.w;
    if (out32) ((float4*)(out32 + (size_t)row * 1024))[tid] = o;
    if (out16) {
        f16x4 h;
        h[0] = (_Float16)o.x; h[1] = (_Float16)o.y; h[2] = (_Float16)o.z; h[3] = (_Float16)o.w;
        *(f16x4*)(out16 + (size_t)row * 1024 + tid * 4) = h;
    }
}

// fp32 -> fp16 elementwise (float4 granularity)
__global__ __launch_bounds__(256) void cast_f16(const float* __restrict__ in,
                                                _Float16* __restrict__ out, int n4)
{
    const int i = blockIdx.x * 256 + threadIdx.x;
    if (i < n4) {
        const float4 v = ((const float4*)in)[i];
        f16x4 h;
        h[0] = (_Float16)v.x; h[1] = (_Float16)v.y; h[2] = (_Float16)v.z; h[3] = (_Float16)v.w;
        ((f16x4*)out)[i] = h;
    }
}

// dst[n][k] = (f16) src[k][n] — LDS-tiled transpose, K,N multiples of 64
__global__ __launch_bounds__(256) void transpose_cast(const float* __restrict__ src,
                                                      _Float16* __restrict__ dst, int K, int N)
{
    __shared__ float tile[64][65];
    const int n0 = blockIdx.x * 64, k0 = blockIdx.y * 64;
    const int tid = threadIdx.x;
#pragma unroll
    for (int it = 0; it < 16; ++it) {
        const int idx = it * 256 + tid;
        const int r = idx >> 6, c = idx & 63;
        tile[r][c] = src[(size_t)(k0 + r) * N + n0 + c];
    }
    __syncthreads();
#pragma unroll
    for (int it = 0; it < 16; ++it) {
        const int idx = it * 256 + tid;
        const int r = idx >> 6, c = idx & 63;
        dst[(size_t)(n0 + r) * K + k0 + c] = (_Float16)tile[c][r];
    }
}

// Wqkv_bt[n][d] = W{q|k|v}[h][d][kk]  (n = which*1024 + h*64 + kk)
__global__ __launch_bounds__(256) void pack_qkv_w(const float* __restrict__ Wq,
                                                  const float* __restrict__ Wk,
                                                  const float* __restrict__ Wv,
                                                  _Float16* __restrict__ dst)
{
    __shared__ float tile[64][65];
    const int n0 = blockIdx.x * 64, d0 = blockIdx.y * 64;
    const int which = n0 >> 10, hh = (n0 >> 6) & 15;
    const float* W = which == 0 ? Wq : (which == 1 ? Wk : Wv);
    const int tid = threadIdx.x;
#pragma unroll
    for (int it = 0; it < 16; ++it) {
        const int idx = it * 256 + tid;
        const int r = idx >> 6, c = idx & 63;
        tile[r][c] = W[((size_t)hh * 1024 + d0 + r) * 64 + c];
    }
    __syncthreads();
#pragma unroll
    for (int it = 0; it < 16; ++it) {
        const int idx = it * 256 + tid;
        const int r = idx >> 6, c = idx & 63;
        dst[(size_t)(n0 + r) * 1024 + d0 + c] = (_Float16)tile[c][r];
    }
}

extern "C" void kernel_launch(void* const* d_in, const int* in_sizes, int n_in,
                              void* d_out, int out_size, void* d_ws, size_t ws_size,
                              hipStream_t stream)
{
    const float* x    = (const float*)d_in[0];
    const float* Wq   = (const float*)d_in[1];
    const float* Wk   = (const float*)d_in[2];
    const float* Wv   = (const float*)d_in[3];
    const float* Wo   = (const float*)d_in[4];
    const float* ln1g = (const float*)d_in[5];
    const float* ln1b = (const float*)d_in[6];
    const float* W1   = (const float*)d_in[7];
    const float* b1   = (const float*)d_in[8];
    const float* W2   = (const float*)d_in[9];
    const float* b2   = (const float*)d_in[10];
    const float* ln2g = (const float*)d_in[11];
    const float* ln2b = (const float*)d_in[12];
    float* out = (float*)d_out;

    char* ws = (char*)d_ws;
    size_t off = 0;
    auto alloc = [&](size_t bytes) {
        void* p = ws + off;
        off += (bytes + 255) & ~(size_t)255;
        return p;
    };
    _Float16* x_h   = (_Float16*)alloc(8192ULL * 1024 * 2);
    _Float16* wqkv  = (_Float16*)alloc(3072ULL * 1024 * 2);
    _Float16* wo_t  = (_Float16*)alloc(1024ULL * 1024 * 2);
    _Float16* w1_t  = (_Float16*)alloc(4096ULL * 1024 * 2);
    _Float16* w2_t  = (_Float16*)alloc(1024ULL * 4096 * 2);
    _Float16* qbuf  = (_Float16*)alloc(8192ULL * 1024 * 2);
    _Float16* kbuf  = (_Float16*)alloc(8192ULL * 1024 * 2);
    _Float16* vt    = (_Float16*)alloc(8192ULL * 1024 * 2);
    _Float16* ctx   = (_Float16*)alloc(8192ULL * 1024 * 2);
    _Float16* ff1   = qbuf;  // reuse after attention+Wo
    float*    resid = (float*)alloc(8192ULL * 1024 * 4);
    float*    h1f   = (float*)alloc(8192ULL * 1024 * 4);
    _Float16* h1h   = (_Float16*)alloc(8192ULL * 1024 * 2);
    if (off > ws_size) return;

    // weight/activation packing
    cast_f16<<<8192, 256, 0, stream>>>(x, x_h, 2097152);
    pack_qkv_w<<<dim3(48, 16), 256, 0, stream>>>(Wq, Wk, Wv, wqkv);
    transpose_cast<<<dim3(16, 16), 256, 0, stream>>>(Wo, wo_t, 1024, 1024);
    transpose_cast<<<dim3(64, 16), 256, 0, stream>>>(W1, w1_t, 1024, 4096);
    transpose_cast<<<dim3(16, 64), 256, 0, stream>>>(W2, w2_t, 4096, 1024);

    // QKV projection (256^2 deep-pipelined, scattered epilogue; q pre-scaled)
    gemm256<0><<<dim3(32, 12), 512, 0, stream>>>(x_h, wqkv, 8192, 3072, 1024,
                                                 nullptr, qbuf, kbuf, vt);
    // causal flash attention
    attn_kernel<<<dim3(16, 64), 256, 0, stream>>>(qbuf, kbuf, vt, ctx);
    // output projection + residual (128^2)
    gemm_bt<1><<<dim3(64, 8), 256, 0, stream>>>(ctx, wo_t, 8192, 1024, 1024,
                                                x, nullptr, resid);
    ln_kernel<<<8192, 256, 0, stream>>>(resid, ln1g, ln1b, h1f, h1h);
    // FFN1 (256^2 deep-pipelined, relu+bias epilogue)
    gemm256<2><<<dim3(32, 16), 512, 0, stream>>>(h1h, w1_t, 8192, 4096, 1024,
                                                 b1, ff1, nullptr, nullptr);
    // FFN2 (128^2) + residual + bias
    gemm_bt<3><<<dim3(64, 8), 256, 0, stream>>>(ff1, w2_t, 8192, 1024, 4096,
                                                b2, h1f, resid);
    ln_kernel<<<8192, 256, 0, stream>>>(resid, ln2g, ln2b, out, nullptr);
}

// Round 9
// 386.765 us; speedup vs baseline: 1.0754x; 1.0754x over previous
//
#include <hip/hip_runtime.h>

#define DEV __device__ __forceinline__

using f16x8 = _Float16 __attribute__((ext_vector_type(8)));
using f16x4 = _Float16 __attribute__((ext_vector_type(4)));
using f32x4 = float __attribute__((ext_vector_type(4)));

DEV f32x4 mfma16(f16x8 a, f16x8 b, f32x4 c) {
    return __builtin_amdgcn_mfma_f32_16x16x32_f16(a, b, c, 0, 0, 0);
}

DEV void gload16(const void* g, void* l) {
    __builtin_amdgcn_global_load_lds(
        (const __attribute__((address_space(1))) void*)g,
        (__attribute__((address_space(3))) void*)l, 16, 0, 0);
}

// ---------------------------------------------------------------------------
// GEMM: C[M,N] = A[M,K] (f16 row-major) * Bt[N,K]^T (f16, N-major "BT" layout)
// 128x128 tile, BK=64, 4 waves (2x2), mfma_f32_16x16x32_f16, XOR-swizzled LDS.
// This structure's ceiling is ~850-900 TF (m97-class); the 256^2 deep-pipe
// attempt (R8) hit the m141 order-pinning trap (515 TF) and was reverted.
// MODE 0: QKV scatter epilogue  (o0=q [bh][s][dk] scaled by log2e/sqrt(D),
//         o1=k [bh][s][dk], o2=vT [bh][dv][s])
// MODE 1: resid1 = acc + x      (ep0 = x fp32, o0 = fp32)
// MODE 2: ff1 = relu(acc + b1)  (ep0 = b1,     o0 = f16)
// MODE 3: resid2 = acc + b2 + h1f (ep0 = b2, ep1 = h1f, o0 = fp32)
// ---------------------------------------------------------------------------
template <int MODE>
__global__ __launch_bounds__(256, 2) void gemm_bt(
    const _Float16* __restrict__ A, const _Float16* __restrict__ Bt,
    int M, int N, int K,
    const float* __restrict__ ep0, const float* __restrict__ ep1,
    void* __restrict__ o0, void* __restrict__ o1, void* __restrict__ o2)
{
    __shared__ __align__(16) _Float16 As[128 * 64];
    __shared__ __align__(16) _Float16 Bs[128 * 64];
    const int tid  = threadIdx.x;
    const int wave = tid >> 6, lane = tid & 63;
    const int l16  = lane & 15, g = lane >> 4;
    const int m0 = blockIdx.x * 128, n0 = blockIdx.y * 128;
    const int wm = (wave >> 1) * 64, wn = (wave & 1) * 64;

    f32x4 acc[4][4] = {};

    for (int kt = 0; kt < K; kt += 64) {
#pragma unroll
        for (int it = 0; it < 4; ++it) {  // stage A tile (16 KB)
            const int off  = it * 4096 + tid * 16;
            const int row  = off >> 7;
            const int colb = (off & 127) ^ ((row & 7) << 4);  // inverse swizzle on source
            gload16(A + (size_t)(m0 + row) * K + kt + (colb >> 1), (char*)As + off);
        }
#pragma unroll
        for (int it = 0; it < 4; ++it) {  // stage B tile
            const int off  = it * 4096 + tid * 16;
            const int row  = off >> 7;
            const int colb = (off & 127) ^ ((row & 7) << 4);
            gload16(Bt + (size_t)(n0 + row) * K + kt + (colb >> 1), (char*)Bs + off);
        }
        __syncthreads();  // vmcnt(0) drain + barrier
#pragma unroll
        for (int kk = 0; kk < 2; ++kk) {
            f16x8 af[4], bfv[4];
#pragma unroll
            for (int i = 0; i < 4; ++i) {
                const int ar = wm + i * 16 + l16;
                const int cb = ((kk * 32 + g * 8) << 1) ^ ((ar & 7) << 4);
                af[i] = *(const f16x8*)((const char*)As + (ar << 7) + cb);
            }
#pragma unroll
            for (int j = 0; j < 4; ++j) {
                const int br = wn + j * 16 + l16;
                const int cb = ((kk * 32 + g * 8) << 1) ^ ((br & 7) << 4);
                bfv[j] = *(const f16x8*)((const char*)Bs + (br << 7) + cb);
            }
#pragma unroll
            for (int i = 0; i < 4; ++i)
#pragma unroll
                for (int j = 0; j < 4; ++j)
                    acc[i][j] = mfma16(af[i], bfv[j], acc[i][j]);
        }
        __syncthreads();
    }

#pragma unroll
    for (int i = 0; i < 4; ++i) {
#pragma unroll
        for (int j = 0; j < 4; ++j) {
#pragma unroll
            for (int r = 0; r < 4; ++r) {
                const int m = m0 + wm + i * 16 + g * 4 + r;   // D row = (lane>>4)*4+reg
                const int n = n0 + wn + j * 16 + l16;          // D col = lane&15
                const float val = acc[i][j][r];
                if constexpr (MODE == 0) {
                    const int b = m >> 11, s = m & 2047;
                    const int which = n >> 10, hh = (n >> 6) & 15, dd = n & 63;
                    const size_t bh = (size_t)(b * 16 + hh);
                    if (which == 0) {
                        // q pre-scaled by log2(e)/sqrt(D) for exp2-domain softmax
                        ((_Float16*)o0)[(bh * 2048 + s) * 64 + dd] =
                            (_Float16)(val * 0.04508422f);
                    } else if (which == 1) {
                        ((_Float16*)o1)[(bh * 2048 + s) * 64 + dd] = (_Float16)val;
                    } else {
                        ((_Float16*)o2)[(bh * 64 + dd) * 2048 + s] = (_Float16)val;
                    }
                } else if constexpr (MODE == 1) {
                    const size_t idx = (size_t)m * N + n;
                    ((float*)o0)[idx] = val + ep0[idx];
                } else if constexpr (MODE == 2) {
                    float v = val + ep0[n];
                    ((_Float16*)o0)[(size_t)m * N + n] = (_Float16)(v > 0.f ? v : 0.f);
                } else {
                    const size_t idx = (size_t)m * N + n;
                    ((float*)o0)[idx] = val + ep0[n] + ep1[idx];
                }
            }
        }
    }
}

// stage one 64-key K,V tile (8 KB each) into the given LDS buffers.
DEV void stage_kv(const _Float16* __restrict__ Kh, const _Float16* __restrict__ Vh,
                  int kb0, char* ksb, char* vsb, int tid)
{
#pragma unroll
    for (int it = 0; it < 2; ++it) {
        const int off  = it * 4096 + tid * 16;
        const int row  = off >> 7;
        const int colb = (off & 127) ^ ((row & 7) << 4);
        gload16(Kh + (size_t)(kb0 + row) * 64 + (colb >> 1), ksb + off);
    }
#pragma unroll
    for (int it = 0; it < 2; ++it) {
        const int off  = it * 4096 + tid * 16;
        const int row  = off >> 7;
        const int colb = (off & 127) ^ ((row & 7) << 4);
        gload16(Vh + (size_t)row * 2048 + kb0 + (colb >> 1), vsb + off);
    }
}

// ---------------------------------------------------------------------------
// Flash attention, causal, block-cooperative double-buffered KV staging with
// counted vmcnt (R7 structure); exp2 via __builtin_amdgcn_exp2f (raw
// v_exp_f32 — the R7 exp2f libcall was a VALU regression).
// ---------------------------------------------------------------------------
__global__ __launch_bounds__(256, 4) void attn_kernel(
    const _Float16* __restrict__ Q, const _Float16* __restrict__ Kb,
    const _Float16* __restrict__ Vt, _Float16* __restrict__ ctx)
{
    __shared__ __align__(16) char smem[40960];
    // [0,16384) K dbuf [2][64][64]; [16384,32768) V dbuf [2][64][64];
    // [32768,40960) P [4][16][64] f16 stride 128 B — all XOR-swizzled.
    const int tid = threadIdx.x;
    const int w = tid >> 6, lane = tid & 63;
    const int l16 = lane & 15, g = lane >> 4;
    const int bh = blockIdx.y;
    const int b = bh >> 4, h = bh & 15;
    const int tA = blockIdx.x;              // 0..15

    const _Float16* Kh = Kb + (size_t)bh * 2048 * 64;
    const _Float16* Vh = Vt + (size_t)bh * 64 * 2048;
    const int swl = (l16 & 7) << 4;
    char* prow = smem + 32768 + w * 2048 + l16 * 128;

    for (int half = 0; half < 2; ++half) {
        const int T = half ? (31 - tA) : tA;        // q-block index, 0..31
        const int qbase = T * 64 + w * 16;
        const int qg = qbase + l16;
        const int nt = T + 1;

        const _Float16* qrow = Q + ((size_t)bh * 2048 + qg) * 64;
        const f16x8 qf0 = *(const f16x8*)(qrow + g * 8);
        const f16x8 qf1 = *(const f16x8*)(qrow + 32 + g * 8);

        f32x4 cacc[4] = {};
        float m_run = -INFINITY, l_run = 0.f;

        stage_kv(Kh, Vh, 0, smem, smem + 16384, tid);
        if (nt > 1) stage_kv(Kh, Vh, 64, smem + 8192, smem + 24576, tid);

        for (int kt = 0; kt < nt; ++kt) {
            const int bufo = (kt & 1) << 13;
            char* kbuf = smem + bufo;
            char* vbuf = smem + 16384 + bufo;

            if (kt + 1 < nt) asm volatile("s_waitcnt vmcnt(4)" ::: "memory");
            else             asm volatile("s_waitcnt vmcnt(0)" ::: "memory");
            __builtin_amdgcn_s_barrier();
            __builtin_amdgcn_sched_barrier(0);

            f32x4 st[4];
            __builtin_amdgcn_s_setprio(1);
#pragma unroll
            for (int s = 0; s < 4; ++s) {
                const char* kr = kbuf + (16 * s + l16) * 128;
                const f16x8 klo = *(const f16x8*)(kr + ((g * 16) ^ swl));
                const f16x8 khi = *(const f16x8*)(kr + ((64 + g * 16) ^ swl));
                f32x4 a0 = {0.f, 0.f, 0.f, 0.f};
                a0 = mfma16(klo, qf0, a0);
                st[s] = mfma16(khi, qf1, a0);
            }
            __builtin_amdgcn_s_setprio(0);

            if (kt == nt - 1) {
#pragma unroll
                for (int s = 0; s < 4; ++s)
#pragma unroll
                    for (int r = 0; r < 4; ++r) {
                        const int kg = kt * 64 + s * 16 + g * 4 + r;
                        if (kg > qg) st[s][r] = -INFINITY;
                    }
            }

            float tmax = st[0][0];
#pragma unroll
            for (int s = 0; s < 4; ++s)
#pragma unroll
                for (int r = 0; r < 4; ++r) tmax = fmaxf(tmax, st[s][r]);
            tmax = fmaxf(tmax, __shfl_xor(tmax, 16));
            tmax = fmaxf(tmax, __shfl_xor(tmax, 32));

            if (__any(tmax > m_run)) {
                const float m_new = fmaxf(m_run, tmax);
                const float alpha = __builtin_amdgcn_exp2f(m_run - m_new);
                m_run = m_new;
                l_run *= alpha;
                f32x4 al;
#pragma unroll
                for (int r = 0; r < 4; ++r) al[r] = __shfl(alpha, g * 4 + r);
#pragma unroll
                for (int jt = 0; jt < 4; ++jt)
#pragma unroll
                    for (int r = 0; r < 4; ++r) cacc[jt][r] *= al[r];
            }

            float tsum = 0.f;
#pragma unroll
            for (int s = 0; s < 4; ++s) {
                f16x4 p;
#pragma unroll
                for (int r = 0; r < 4; ++r) {
                    const float e = __builtin_amdgcn_exp2f(st[s][r] - m_run);
                    tsum += e;
                    p[r] = (_Float16)e;
                }
                *(f16x4*)(prow + ((s * 32 + g * 8) ^ swl)) = p;
            }
            tsum += __shfl_xor(tsum, 16);
            tsum += __shfl_xor(tsum, 32);
            l_run += tsum;

            const f16x8 pf0 = *(const f16x8*)(prow + ((g * 16) ^ swl));
            const f16x8 pf1 = *(const f16x8*)(prow + ((64 + g * 16) ^ swl));
            __builtin_amdgcn_s_setprio(1);
#pragma unroll
            for (int jt = 0; jt < 4; ++jt) {
                const char* vr = vbuf + (jt * 16 + l16) * 128;
                const f16x8 vlo = *(const f16x8*)(vr + ((g * 16) ^ swl));
                const f16x8 vhi = *(const f16x8*)(vr + ((64 + g * 16) ^ swl));
                cacc[jt] = mfma16(pf0, vlo, cacc[jt]);
                cacc[jt] = mfma16(pf1, vhi, cacc[jt]);
            }
            __builtin_amdgcn_s_setprio(0);

            __builtin_amdgcn_sched_barrier(0);
            __builtin_amdgcn_s_barrier();
            if (kt + 2 < nt)
                stage_kv(Kh, Vh, (kt + 2) * 64, kbuf, vbuf, tid);
        }

        __builtin_amdgcn_s_barrier();

        const float inv = 1.f / l_run;
        f32x4 il;
#pragma unroll
        for (int r = 0; r < 4; ++r) il[r] = __shfl(inv, g * 4 + r);
#pragma unroll
        for (int jt = 0; jt < 4; ++jt)
#pragma unroll
            for (int r = 0; r < 4; ++r)
                ctx[((size_t)b * 2048 + qbase + g * 4 + r) * 1024 + h * 64 + jt * 16 + l16]
                    = (_Float16)(cacc[jt][r] * il[r]);
    }
}

// ---------------------------------------------------------------------------
// LayerNorm over rows of 1024 fp32; optional fp32 and f16 outputs.
// ---------------------------------------------------------------------------
__global__ __launch_bounds__(256) void ln_kernel(
    const float* __restrict__ in, const float* __restrict__ gam, const float* __restrict__ bet,
    float* __restrict__ out32, _Float16* __restrict__ out16)
{
    const int row = blockIdx.x, tid = threadIdx.x;
    const float4 x = ((const float4*)(in + (size_t)row * 1024))[tid];
    float s  = x.x + x.y + x.z + x.w;
    float s2 = x.x * x.x + x.y * x.y + x.z * x.z + x.w * x.w;
#pragma unroll
    for (int o = 32; o > 0; o >>= 1) {
        s  += __shfl_xor(s, o);
        s2 += __shfl_xor(s2, o);
    }
    __shared__ float red[8];
    if ((tid & 63) == 0) { red[tid >> 6] = s; red[4 + (tid >> 6)] = s2; }
    __syncthreads();
    const float S  = red[0] + red[1] + red[2] + red[3];
    const float S2 = red[4] + red[5] + red[6] + red[7];
    const float mu = S * (1.f / 1024.f);
    const float ir = rsqrtf(S2 * (1.f / 1024.f) - mu * mu + 1e-5f);
    const float4 gv = ((const float4*)gam)[tid];
    const float4 bv = ((const float4*)bet)[tid];
    float4 o;
    o.x = (x.x - mu) * ir * gv.x + bv.x;
    o.y = (x.y - mu) * ir * gv.y + bv.y;
    o.z = (x.z - mu) * ir * gv.z + bv.z;
    o.w = (x.w - mu) * ir * gv.w + bv.w;
    if (out32) ((float4*)(out32 + (size_t)row * 1024))[tid] = o;
    if (out16) {
        f16x4 h;
        h[0] = (_Float16)o.x; h[1] = (_Float16)o.y; h[2] = (_Float16)o.z; h[3] = (_Float16)o.w;
        *(f16x4*)(out16 + (size_t)row * 1024 + tid * 4) = h;
    }
}

// fp32 -> fp16 elementwise (float4 granularity)
__global__ __launch_bounds__(256) void cast_f16(const float* __restrict__ in,
                                                _Float16* __restrict__ out, int n4)
{
    const int i = blockIdx.x * 256 + threadIdx.x;
    if (i < n4) {
        const float4 v = ((const float4*)in)[i];
        f16x4 h;
        h[0] = (_Float16)v.x; h[1] = (_Float16)v.y; h[2] = (_Float16)v.z; h[3] = (_Float16)v.w;
        ((f16x4*)out)[i] = h;
    }
}

// dst[n][k] = (f16) src[k][n] — LDS-tiled transpose, K,N multiples of 64
__global__ __launch_bounds__(256) void transpose_cast(const float* __restrict__ src,
                                                      _Float16* __restrict__ dst, int K, int N)
{
    __shared__ float tile[64][65];
    const int n0 = blockIdx.x * 64, k0 = blockIdx.y * 64;
    const int tid = threadIdx.x;
#pragma unroll
    for (int it = 0; it < 16; ++it) {
        const int idx = it * 256 + tid;
        const int r = idx >> 6, c = idx & 63;
        tile[r][c] = src[(size_t)(k0 + r) * N + n0 + c];
    }
    __syncthreads();
#pragma unroll
    for (int it = 0; it < 16; ++it) {
        const int idx = it * 256 + tid;
        const int r = idx >> 6, c = idx & 63;
        dst[(size_t)(n0 + r) * K + k0 + c] = (_Float16)tile[c][r];
    }
}

// Wqkv_bt[n][d] = W{q|k|v}[h][d][kk]  (n = which*1024 + h*64 + kk)
__global__ __launch_bounds__(256) void pack_qkv_w(const float* __restrict__ Wq,
                                                  const float* __restrict__ Wk,
                                                  const float* __restrict__ Wv,
                                                  _Float16* __restrict__ dst)
{
    __shared__ float tile[64][65];
    const int n0 = blockIdx.x * 64, d0 = blockIdx.y * 64;
    const int which = n0 >> 10, hh = (n0 >> 6) & 15;
    const float* W = which == 0 ? Wq : (which == 1 ? Wk : Wv);
    const int tid = threadIdx.x;
#pragma unroll
    for (int it = 0; it < 16; ++it) {
        const int idx = it * 256 + tid;
        const int r = idx >> 6, c = idx & 63;
        tile[r][c] = W[((size_t)hh * 1024 + d0 + r) * 64 + c];
    }
    __syncthreads();
#pragma unroll
    for (int it = 0; it < 16; ++it) {
        const int idx = it * 256 + tid;
        const int r = idx >> 6, c = idx & 63;
        dst[(size_t)(n0 + r) * 1024 + d0 + c] = (_Float16)tile[c][r];
    }
}

extern "C" void kernel_launch(void* const* d_in, const int* in_sizes, int n_in,
                              void* d_out, int out_size, void* d_ws, size_t ws_size,
                              hipStream_t stream)
{
    const float* x    = (const float*)d_in[0];
    const float* Wq   = (const float*)d_in[1];
    const float* Wk   = (const float*)d_in[2];
    const float* Wv   = (const float*)d_in[3];
    const float* Wo   = (const float*)d_in[4];
    const float* ln1g = (const float*)d_in[5];
    const float* ln1b = (const float*)d_in[6];
    const float* W1   = (const float*)d_in[7];
    const float* b1   = (const float*)d_in[8];
    const float* W2   = (const float*)d_in[9];
    const float* b2   = (const float*)d_in[10];
    const float* ln2g = (const float*)d_in[11];
    const float* ln2b = (const float*)d_in[12];
    float* out = (float*)d_out;

    char* ws = (char*)d_ws;
    size_t off = 0;
    auto alloc = [&](size_t bytes) {
        void* p = ws + off;
        off += (bytes + 255) & ~(size_t)255;
        return p;
    };
    _Float16* x_h   = (_Float16*)alloc(8192ULL * 1024 * 2);
    _Float16* wqkv  = (_Float16*)alloc(3072ULL * 1024 * 2);
    _Float16* wo_t  = (_Float16*)alloc(1024ULL * 1024 * 2);
    _Float16* w1_t  = (_Float16*)alloc(4096ULL * 1024 * 2);
    _Float16* w2_t  = (_Float16*)alloc(1024ULL * 4096 * 2);
    _Float16* qbuf  = (_Float16*)alloc(8192ULL * 1024 * 2);
    _Float16* kbuf  = (_Float16*)alloc(8192ULL * 1024 * 2);
    _Float16* vt    = (_Float16*)alloc(8192ULL * 1024 * 2);
    _Float16* ctx   = (_Float16*)alloc(8192ULL * 1024 * 2);
    _Float16* ff1   = qbuf;  // reuse after attention+Wo
    float*    resid = (float*)alloc(8192ULL * 1024 * 4);
    float*    h1f   = (float*)alloc(8192ULL * 1024 * 4);
    _Float16* h1h   = (_Float16*)alloc(8192ULL * 1024 * 2);
    if (off > ws_size) return;

    // weight/activation packing
    cast_f16<<<8192, 256, 0, stream>>>(x, x_h, 2097152);
    pack_qkv_w<<<dim3(48, 16), 256, 0, stream>>>(Wq, Wk, Wv, wqkv);
    transpose_cast<<<dim3(16, 16), 256, 0, stream>>>(Wo, wo_t, 1024, 1024);
    transpose_cast<<<dim3(64, 16), 256, 0, stream>>>(W1, w1_t, 1024, 4096);
    transpose_cast<<<dim3(16, 64), 256, 0, stream>>>(W2, w2_t, 4096, 1024);

    // QKV projection (fused, scattered epilogue; q pre-scaled)
    gemm_bt<0><<<dim3(64, 24), 256, 0, stream>>>(x_h, wqkv, 8192, 3072, 1024,
                                                 nullptr, nullptr, qbuf, kbuf, vt);
    // causal flash attention
    attn_kernel<<<dim3(16, 64), 256, 0, stream>>>(qbuf, kbuf, vt, ctx);
    // output projection + residual
    gemm_bt<1><<<dim3(64, 8), 256, 0, stream>>>(ctx, wo_t, 8192, 1024, 1024,
                                                x, nullptr, resid, nullptr, nullptr);
    ln_kernel<<<8192, 256, 0, stream>>>(resid, ln1g, ln1b, h1f, h1h);
    // FFN
    gemm_bt<2><<<dim3(64, 32), 256, 0, stream>>>(h1h, w1_t, 8192, 4096, 1024,
                                                 b1, nullptr, ff1, nullptr, nullptr);
    gemm_bt<3><<<dim3(64, 8), 256, 0, stream>>>(ff1, w2_t, 8192, 1024, 4096,
                                                b2, h1f, resid, nullptr, nullptr);
    ln_kernel<<<8192, 256, 0, stream>>>(resid, ln2g, ln2b, out, nullptr);
}